// Round 5
// baseline (364.025 us; speedup 1.0000x reference)
//
#include <hip/hip_runtime.h>

#define SEQ    2048
#define DMODEL 512
#define NHEAD  8
#define HDIM   64
#define BATCH  4

#define LOG2E  1.4426950408889634f
#define QSCALE 0.18033688011112042f   // 0.125 * log2(e), folded into Q proj

typedef float f32x4  __attribute__((ext_vector_type(4)));
typedef float f32x16 __attribute__((ext_vector_type(16)));
typedef _Float16 h16x8 __attribute__((ext_vector_type(8)));
typedef _Float16 h16x2 __attribute__((ext_vector_type(2)));

union U4H { uint4 u; h16x8 h; };
union U1H2 { unsigned int u; h16x2 h; };

static __device__ inline h16x2 pkrtz(float a, float b) {
    return __builtin_bit_cast(h16x2, __builtin_amdgcn_cvt_pkrtz(a, b));
}
static __device__ inline unsigned short f2h(float x) {
    _Float16 h = (_Float16)x;
    return __builtin_bit_cast(unsigned short, h);
}
static __device__ inline float dot2acc(h16x2 a, h16x2 b, float c) {
    return c + (float)a[0] * (float)b[0] + (float)a[1] * (float)b[1];
}
// async 16B/lane global->LDS copy (lds base must be wave-uniform)
static __device__ inline void async_cp16(const void* g, void* l) {
    __builtin_amdgcn_global_load_lds(
        (const __attribute__((address_space(1))) unsigned int*)g,
        (__attribute__((address_space(3))) unsigned int*)l,
        16, 0, 0);
}

// ---------------------------------------------------------------------------
// Transpose-cast the four 512x512 weight matrices: W[k][n] -> Wt[n][k] fp16
// ---------------------------------------------------------------------------
__global__ __launch_bounds__(256) void transpose_cast_w(
    const float* __restrict__ s0, const float* __restrict__ s1,
    const float* __restrict__ s2, const float* __restrict__ s3,
    unsigned short* __restrict__ d0, unsigned short* __restrict__ d1,
    unsigned short* __restrict__ d2, unsigned short* __restrict__ d3)
{
    const float* S; unsigned short* D;
    switch (blockIdx.z) {
        case 0: S = s0; D = d0; break;
        case 1: S = s1; D = d1; break;
        case 2: S = s2; D = d2; break;
        default: S = s3; D = d3; break;
    }
    __shared__ float T[32][33];
    const int t = threadIdx.x;
    const int r = t >> 3, c = (t & 7) * 4;
    const int k0 = blockIdx.x * 32, n0 = blockIdx.y * 32;
    float4 v = *(const float4*)&S[(size_t)(k0 + r) * DMODEL + n0 + c];
    T[r][c] = v.x; T[r][c + 1] = v.y; T[r][c + 2] = v.z; T[r][c + 3] = v.w;
    __syncthreads();
    ushort4 o;
    o.x = f2h(T[c + 0][r]); o.y = f2h(T[c + 1][r]);
    o.z = f2h(T[c + 2][r]); o.w = f2h(T[c + 3][r]);
    *(ushort4*)&D[(size_t)(n0 + r) * DMODEL + k0 + c] = o;
}

// ---------------------------------------------------------------------------
// Mask pre-pass: em = fp16(exp(mask)), permuted to the S^T C-layout order.
// Element (q,k): kt=k>>6, kl=k&63 = 32*mt + 8*g + 4*hl + r
//   -> em[((kt*SEQ+q)*64) + hl*32 + mt*16 + g*4 + r]
// ---------------------------------------------------------------------------
__global__ __launch_bounds__(256) void prep_mask(
    const float* __restrict__ mask, unsigned short* __restrict__ mp)
{
    int i = blockIdx.x * 256 + threadIdx.x;     // float4 index
    int k = (i * 4) & (SEQ - 1);
    int q = (i * 4) >> 11;
    float4 v = ((const float4*)mask)[i];
    int kt = k >> 6, kl = k & 63;
    int mt = kl >> 5, g = (kl >> 3) & 3, hl = (kl >> 2) & 1;
    size_t base = ((size_t)kt * SEQ + q) * 64 + hl * 32 + mt * 16 + g * 4;
    ushort4 o;
    o.x = f2h(__builtin_amdgcn_exp2f(v.x * LOG2E));
    o.y = f2h(__builtin_amdgcn_exp2f(v.y * LOG2E));
    o.z = f2h(__builtin_amdgcn_exp2f(v.z * LOG2E));
    o.w = f2h(__builtin_amdgcn_exp2f(v.w * LOG2E));
    *(ushort4*)&mp[base] = o;
}

// ---------------------------------------------------------------------------
// Per-head transpose of the V projection (f16 bits, dtype-agnostic):
// vb[b*SEQ+key][h*64+dv] -> vT[((b*8+h)*64+dv)*SEQ + key]
// ---------------------------------------------------------------------------
__global__ __launch_bounds__(256) void transpose_v(
    const unsigned short* __restrict__ vb, unsigned short* __restrict__ vT)
{
    const int t = threadIdx.x;
    const int key0 = blockIdx.x * 64;
    const int bh = blockIdx.y, b = bh >> 3, h = bh & 7;
    #pragma unroll
    for (int p = 0; p < 2; p++) {
        int cid = p * 256 + t;
        int dv = cid >> 3, kch = cid & 7;
        unsigned short tmp[8];
        #pragma unroll
        for (int j = 0; j < 8; j++)
            tmp[j] = vb[(size_t)(b * SEQ + key0 + kch * 8 + j) * DMODEL + h * HDIM + dv];
        uint4 o;
        o.x = tmp[0] | ((unsigned)tmp[1] << 16);
        o.y = tmp[2] | ((unsigned)tmp[3] << 16);
        o.z = tmp[4] | ((unsigned)tmp[5] << 16);
        o.w = tmp[6] | ((unsigned)tmp[7] << 16);
        *(uint4*)&vT[(size_t)((b * NHEAD + h) * HDIM + dv) * SEQ + key0 + kch * 8] = o;
    }
}

// ---------------------------------------------------------------------------
// GEMM core: C[..][512] = A[..][512] @ Wt[512][512]^T + bias (Wt is [n][k]).
// 128x128 tile, BK=32, 256 thr = 4 waves, wave = 64m x 64n (4x4 MFMA 16x16x32).
// A_FP32: fused fp32->f16 cast in staging; else async global_load_lds f16.
// ---------------------------------------------------------------------------
template <int A_FP32, int OUT_F16>
static __device__ inline void gemm_core(
    const void* __restrict__ Ap, const unsigned short* __restrict__ Bt,
    const float* __restrict__ bias, void* __restrict__ Cout, float oscale,
    int bm, int bn)
{
    __shared__ __align__(16) unsigned short As[128 * 32];
    __shared__ __align__(16) unsigned short Bs[128 * 32];

    const int t = threadIdx.x;
    const int lane = t & 63, w = t >> 6;
    const int wm = w >> 1, wn = w & 1;
    const int c = lane & 15, quad = lane >> 4;

    f32x4 acc[4][4] = {};

    for (int k0 = 0; k0 < DMODEL; k0 += 32) {
        if (A_FP32) {
            const float* Af = (const float*)Ap;
            #pragma unroll
            for (int p = 0; p < 4; p++) {
                int cid = p * 256 + t;
                int row = cid >> 3, fc = cid & 7;
                float4 av = *(const float4*)&Af[(size_t)(bm + row) * DMODEL + k0 + fc * 4];
                U1H2 lo, hi;
                lo.h = pkrtz(av.x, av.y);
                hi.h = pkrtz(av.z, av.w);
                uint2 st = make_uint2(lo.u, hi.u);
                *(uint2*)&As[row * 32 + fc * 4] = st;
            }
        } else {
            const unsigned short* Ab = (const unsigned short*)Ap;
            #pragma unroll
            for (int i = 0; i < 2; i++) {
                int row = 32 * w + 16 * i + (lane >> 2);
                const unsigned short* gp = Ab + (size_t)(bm + row) * DMODEL + k0 + (lane & 3) * 8;
                async_cp16(gp, &As[(32 * w + 16 * i) * 32]);
            }
        }
        #pragma unroll
        for (int i = 0; i < 2; i++) {
            int row = 32 * w + 16 * i + (lane >> 2);
            const unsigned short* gp = Bt + (size_t)(bn + row) * DMODEL + k0 + (lane & 3) * 8;
            async_cp16(gp, &Bs[(32 * w + 16 * i) * 32]);
        }
        __syncthreads();

        U4H af[4], bf[4];
        #pragma unroll
        for (int mt = 0; mt < 4; mt++)
            af[mt].u = *(const uint4*)&As[(wm * 64 + mt * 16 + c) * 32 + quad * 8];
        #pragma unroll
        for (int nt = 0; nt < 4; nt++)
            bf[nt].u = *(const uint4*)&Bs[(wn * 64 + nt * 16 + c) * 32 + quad * 8];
        #pragma unroll
        for (int mt = 0; mt < 4; mt++)
            #pragma unroll
            for (int nt = 0; nt < 4; nt++)
                acc[mt][nt] = __builtin_amdgcn_mfma_f32_16x16x32_f16(
                    af[mt].h, bf[nt].h, acc[mt][nt], 0, 0, 0);
        __syncthreads();
    }

    #pragma unroll
    for (int nt = 0; nt < 4; nt++) {
        int ng = bn + wn * 64 + nt * 16 + c;
        float bv = bias[ng];
        #pragma unroll
        for (int mt = 0; mt < 4; mt++) {
            #pragma unroll
            for (int r = 0; r < 4; r++) {
                int mg = bm + wm * 64 + mt * 16 + quad * 4 + r;
                float v = (acc[mt][nt][r] + bv) * oscale;
                if (OUT_F16)
                    ((unsigned short*)Cout)[(size_t)mg * DMODEL + ng] = f2h(v);
                else
                    ((float*)Cout)[(size_t)mg * DMODEL + ng] = v;
            }
        }
    }
}

struct QKVArgs {
    const float *A0, *A1, *A2;
    const unsigned short *W0, *W1, *W2;
    const float *b0, *b1, *b2;
    unsigned short *o0, *o1, *o2;
};

__global__ __launch_bounds__(256) void gemm_qkv(QKVArgs a) {
    const float* A; const unsigned short* W; const float* bias;
    unsigned short* out; float sc;
    switch (blockIdx.z) {
        case 0: A = a.A0; W = a.W0; bias = a.b0; out = a.o0; sc = QSCALE; break;
        case 1: A = a.A1; W = a.W1; bias = a.b1; out = a.o1; sc = 1.0f;  break;
        default: A = a.A2; W = a.W2; bias = a.b2; out = a.o2; sc = 1.0f; break;
    }
    gemm_core<1, 1>(A, W, bias, out, sc, blockIdx.y * 128, blockIdx.x * 128);
}

__global__ __launch_bounds__(256) void gemm_fin(
    const unsigned short* __restrict__ A, const unsigned short* __restrict__ W,
    const float* __restrict__ bias, float* __restrict__ C) {
    gemm_core<0, 0>(A, W, bias, C, 1.0f, blockIdx.y * 128, blockIdx.x * 128);
}

// ---------------------------------------------------------------------------
// Flash attention, 32x32x16 f16 MFMA, S^T trick, no-max softmax (p=exp2(S)*em).
// Block = 128 threads (2 waves) x 64 q rows; wave w owns q = q0+32w+(lane&31).
// LDS planes padded to 65 rows (stride 1040B) -> conflict-free writes+reads.
// Register prefetch of next K/V tile hides global latency under compute.
// ---------------------------------------------------------------------------
__global__ __launch_bounds__(128) void attn3(
    const unsigned short* __restrict__ qb, const unsigned short* __restrict__ kb,
    const unsigned short* __restrict__ vT, const unsigned short* __restrict__ emp,
    unsigned short* __restrict__ X)
{
    __shared__ __align__(16) unsigned short Ks[8 * 65 * 8];
    __shared__ __align__(16) unsigned short Vs[8 * 65 * 8];

    const int t = threadIdx.x;            // 0..127
    const int lane = t & 63, w = t >> 6;  // 2 waves
    const int c32 = lane & 31, hl = lane >> 5;
    const int bh = blockIdx.x, b = bh >> 3, head = bh & 7;
    const int q0 = blockIdx.y * 64;
    const int qg = q0 + w * 32 + c32;

    // hoisted Q B-frags (q pre-scaled by 0.125*log2e in projection)
    const unsigned short* qrow = qb + ((size_t)b * SEQ + qg) * DMODEL + head * HDIM;
    U4H Qf[4];
    #pragma unroll
    for (int s = 0; s < 4; s++)
        Qf[s].u = *(const uint4*)&qrow[s * 16 + hl * 8];

    const unsigned short* kgb = kb + (size_t)b * SEQ * DMODEL + head * HDIM;
    const unsigned short* vgb = vT + (size_t)bh * HDIM * SEQ;

    const int r8p = t >> 3;               // base row for staging (p adds 16)
    const int chp = t & 7;                // feature/key chunk for staging

    uint4 kreg[4], vreg[4];
    #pragma unroll
    for (int p = 0; p < 4; p++) {         // prefetch tile 0
        int r8 = p * 16 + r8p;
        kreg[p] = *(const uint4*)&kgb[(size_t)r8 * DMODEL + chp * 8];
        vreg[p] = *(const uint4*)&vgb[(size_t)r8 * SEQ + 0 + chp * 8];
    }

    f32x16 O0 = {}, O1 = {};
    float lsum = 0.f;

    for (int kt = 0; kt < SEQ / 64; kt++) {
        __syncthreads();                  // prev iter's LDS reads done
        #pragma unroll
        for (int p = 0; p < 4; p++) {
            int r8 = p * 16 + r8p;
            *(uint4*)&Ks[(chp * 65 + r8) * 8] = kreg[p];
            *(uint4*)&Vs[(chp * 65 + r8) * 8] = vreg[p];
        }
        __syncthreads();                  // tiles staged

        if (kt + 1 < SEQ / 64) {          // prefetch next tile (hidden by compute)
            int k0n = (kt + 1) * 64;
            #pragma unroll
            for (int p = 0; p < 4; p++) {
                int r8 = p * 16 + r8p;
                kreg[p] = *(const uint4*)&kgb[(size_t)(k0n + r8) * DMODEL + chp * 8];
                vreg[p] = *(const uint4*)&vgb[(size_t)r8 * SEQ + k0n + chp * 8];
            }
        }

        // em loads (f16, permuted layout)
        const unsigned short* mrow = emp + ((size_t)kt * SEQ + qg) * 64 + hl * 32;
        U4H e0, e1, e2, e3;
        e0.u = *(const uint4*)&mrow[0];
        e1.u = *(const uint4*)&mrow[8];
        e2.u = *(const uint4*)&mrow[16];
        e3.u = *(const uint4*)&mrow[24];

        // ---- S^T = K.Q^T : 2 key-tiles x 4 feature-steps ----
        f32x16 S0 = {}, S1 = {};
        #pragma unroll
        for (int s = 0; s < 4; s++) {
            int fc = 2 * s + hl;
            U4H ka0, ka1;
            ka0.u = *(const uint4*)&Ks[(fc * 65 + c32) * 8];
            ka1.u = *(const uint4*)&Ks[(fc * 65 + 32 + c32) * 8];
            S0 = __builtin_amdgcn_mfma_f32_32x32x16_f16(ka0.h, Qf[s].h, S0, 0, 0, 0);
            S1 = __builtin_amdgcn_mfma_f32_32x32x16_f16(ka1.h, Qf[s].h, S1, 0, 0, 0);
        }

        // ---- softmax: p = exp2(S) * em, f16 pack, l-accumulate ----
        unsigned int Pf[4][4];
        #pragma unroll
        for (int mt = 0; mt < 2; mt++) {
            f32x16 S = mt ? S1 : S0;
            h16x8 ea = (mt ? e2 : e0).h;
            h16x8 eb = (mt ? e3 : e1).h;
            unsigned int u[4][2];
            #pragma unroll
            for (int jj = 0; jj < 4; jj++) {
                h16x2 ex = {ea[2 * jj], ea[2 * jj + 1]};
                h16x2 pk = pkrtz(__builtin_amdgcn_exp2f(S[2 * jj]),
                                 __builtin_amdgcn_exp2f(S[2 * jj + 1]));
                h16x2 pp = pk * ex;
                lsum = dot2acc(pp, pp, lsum) - dot2acc(pp, pp, 0.f) +
                       (float)pp[0] + (float)pp[1];
                u[jj >> 1][jj & 1] = __builtin_bit_cast(unsigned int, pp);
            }
            #pragma unroll
            for (int jj = 4; jj < 8; jj++) {
                h16x2 ex = {eb[2 * jj - 8], eb[2 * jj - 7]};
                h16x2 pk = pkrtz(__builtin_amdgcn_exp2f(S[2 * jj]),
                                 __builtin_amdgcn_exp2f(S[2 * jj + 1]));
                h16x2 pp = pk * ex;
                lsum += (float)pp[0] + (float)pp[1];
                u[jj >> 1][jj & 1] = __builtin_bit_cast(unsigned int, pp);
            }
            // half-wave block exchange (C-layout -> PV B-operand layout)
            unsigned int sA0 = hl ? u[0][0] : u[1][0];
            unsigned int sA1 = hl ? u[0][1] : u[1][1];
            unsigned int sB0 = hl ? u[2][0] : u[3][0];
            unsigned int sB1 = hl ? u[2][1] : u[3][1];
            unsigned int rA0 = (unsigned)__shfl_xor((int)sA0, 32, 64);
            unsigned int rA1 = (unsigned)__shfl_xor((int)sA1, 32, 64);
            unsigned int rB0 = (unsigned)__shfl_xor((int)sB0, 32, 64);
            unsigned int rB1 = (unsigned)__shfl_xor((int)sB1, 32, 64);
            Pf[2 * mt + 0][0] = hl ? rA0 : u[0][0];
            Pf[2 * mt + 0][1] = hl ? rA1 : u[0][1];
            Pf[2 * mt + 0][2] = hl ? u[1][0] : rA0;
            Pf[2 * mt + 0][3] = hl ? u[1][1] : rA1;
            Pf[2 * mt + 1][0] = hl ? rB0 : u[2][0];
            Pf[2 * mt + 1][1] = hl ? rB1 : u[2][1];
            Pf[2 * mt + 1][2] = hl ? u[3][0] : rB0;
            Pf[2 * mt + 1][3] = hl ? u[3][1] : rB1;
        }

        // ---- O^T += V^T . P : 2 dv-tiles x 4 key-steps ----
        #pragma unroll
        for (int s = 0; s < 4; s++) {
            int kc = 2 * s + hl;
            U4H va0, va1, pu;
            va0.u = *(const uint4*)&Vs[(kc * 65 + c32) * 8];
            va1.u = *(const uint4*)&Vs[(kc * 65 + 32 + c32) * 8];
            pu.u = make_uint4(Pf[s][0], Pf[s][1], Pf[s][2], Pf[s][3]);
            O0 = __builtin_amdgcn_mfma_f32_32x32x16_f16(va0.h, pu.h, O0, 0, 0, 0);
            O1 = __builtin_amdgcn_mfma_f32_32x32x16_f16(va1.h, pu.h, O1, 0, 0, 0);
        }
    }

    // ---- epilogue: combine lane-halves' l, scale, f16 store (scrambled) ----
    lsum += __shfl_xor(lsum, 32, 64);
    float inv = 1.0f / lsum;
    unsigned short* xrow = X + (((size_t)head * SEQ + qg) * BATCH + b) * HDIM;
    #pragma unroll
    for (int mt = 0; mt < 2; mt++) {
        f32x16 Ov = mt ? O1 : O0;
        #pragma unroll
        for (int g = 0; g < 4; g++) {
            U1H2 lo, hi;
            lo.h = pkrtz(Ov[g * 4 + 0] * inv, Ov[g * 4 + 1] * inv);
            hi.h = pkrtz(Ov[g * 4 + 2] * inv, Ov[g * 4 + 3] * inv);
            uint2 st = make_uint2(lo.u, hi.u);
            *(uint2*)&xrow[mt * 32 + 8 * g + 4 * hl] = st;
        }
    }
}

// ---------------------------------------------------------------------------
extern "C" void kernel_launch(void* const* d_in, const int* in_sizes, int n_in,
                              void* d_out, int out_size, void* d_ws, size_t ws_size,
                              hipStream_t stream) {
    const float* query = (const float*)d_in[0];
    const float* key_  = (const float*)d_in[1];
    const float* value = (const float*)d_in[2];
    const float* mask  = (const float*)d_in[3];
    const float* Wq = (const float*)d_in[4];
    const float* bq = (const float*)d_in[5];
    const float* Wk = (const float*)d_in[6];
    const float* bk = (const float*)d_in[7];
    const float* Wv = (const float*)d_in[8];
    const float* bv = (const float*)d_in[9];
    const float* Wo = (const float*)d_in[10];
    const float* bo = (const float*)d_in[11];
    float* out = (float*)d_out;

    const size_t NP = (size_t)BATCH * SEQ * DMODEL;   // 4194304
    unsigned short* ws   = (unsigned short*)d_ws;
    unsigned short* qb16 = ws;
    unsigned short* kb16 = qb16 + NP;
    unsigned short* vb16 = kb16 + NP;
    unsigned short* vT16 = vb16 + NP;
    unsigned short* xb16 = vT16 + NP;
    unsigned short* em16 = xb16 + NP;                 // SEQ*SEQ f16
    unsigned short* WqT  = em16 + (size_t)SEQ * SEQ;
    unsigned short* WkT  = WqT + DMODEL * DMODEL;
    unsigned short* WvT  = WkT + DMODEL * DMODEL;
    unsigned short* WoT  = WvT + DMODEL * DMODEL;
    // total ws use ~52 MB

    transpose_cast_w<<<dim3(16, 16, 4), 256, 0, stream>>>(
        Wq, Wk, Wv, Wo, WqT, WkT, WvT, WoT);
    prep_mask<<<dim3(SEQ * SEQ / 4 / 256), 256, 0, stream>>>(mask, em16);

    QKVArgs qa;
    qa.A0 = query; qa.A1 = key_; qa.A2 = value;
    qa.W0 = WqT;   qa.W1 = WkT;  qa.W2 = WvT;
    qa.b0 = bq;    qa.b1 = bk;   qa.b2 = bv;
    qa.o0 = qb16;  qa.o1 = kb16; qa.o2 = vb16;
    gemm_qkv<<<dim3(DMODEL / 128, BATCH * SEQ / 128, 3), 256, 0, stream>>>(qa);

    transpose_v<<<dim3(SEQ / 64, BATCH * NHEAD), 256, 0, stream>>>(vb16, vT16);

    attn3<<<dim3(BATCH * NHEAD, SEQ / 64), 128, 0, stream>>>(
        qb16, kb16, vT16, em16, xb16);

    gemm_fin<<<dim3(DMODEL / 128, BATCH * SEQ / 128), 256, 0, stream>>>(
        xb16, WoT, bo, out);
}

// Round 6
// 265.055 us; speedup vs baseline: 1.3734x; 1.3734x over previous
//
#include <hip/hip_runtime.h>

#define SEQ    2048
#define DMODEL 512
#define NHEAD  8
#define HDIM   64
#define BATCH  4

#define LOG2E  1.4426950408889634f
#define QSCALE 0.18033688011112042f   // 0.125 * log2(e), folded into Q proj

typedef float f32x4  __attribute__((ext_vector_type(4)));
typedef float f32x16 __attribute__((ext_vector_type(16)));
typedef _Float16 h16x8 __attribute__((ext_vector_type(8)));
typedef _Float16 h16x2 __attribute__((ext_vector_type(2)));

union U4H { uint4 u; h16x8 h; };
union U1H2 { unsigned int u; h16x2 h; };

static __device__ inline h16x2 pkrtz(float a, float b) {
    return __builtin_bit_cast(h16x2, __builtin_amdgcn_cvt_pkrtz(a, b));
}
static __device__ inline unsigned short f2h(float x) {
    _Float16 h = (_Float16)x;
    return __builtin_bit_cast(unsigned short, h);
}
// async 16B/lane global->LDS copy (lds base must be wave-uniform)
static __device__ inline void async_cp16(const void* g, void* l) {
    __builtin_amdgcn_global_load_lds(
        (const __attribute__((address_space(1))) unsigned int*)g,
        (__attribute__((address_space(3))) unsigned int*)l,
        16, 0, 0);
}

// ---------------------------------------------------------------------------
// Transpose-cast the four 512x512 weight matrices: W[k][n] -> Wt[n][k] fp16
// ---------------------------------------------------------------------------
__global__ __launch_bounds__(256) void transpose_cast_w(
    const float* __restrict__ s0, const float* __restrict__ s1,
    const float* __restrict__ s2, const float* __restrict__ s3,
    unsigned short* __restrict__ d0, unsigned short* __restrict__ d1,
    unsigned short* __restrict__ d2, unsigned short* __restrict__ d3)
{
    const float* S; unsigned short* D;
    switch (blockIdx.z) {
        case 0: S = s0; D = d0; break;
        case 1: S = s1; D = d1; break;
        case 2: S = s2; D = d2; break;
        default: S = s3; D = d3; break;
    }
    __shared__ float T[32][33];
    const int t = threadIdx.x;
    const int r = t >> 3, c = (t & 7) * 4;
    const int k0 = blockIdx.x * 32, n0 = blockIdx.y * 32;
    float4 v = *(const float4*)&S[(size_t)(k0 + r) * DMODEL + n0 + c];
    T[r][c] = v.x; T[r][c + 1] = v.y; T[r][c + 2] = v.z; T[r][c + 3] = v.w;
    __syncthreads();
    ushort4 o;
    o.x = f2h(T[c + 0][r]); o.y = f2h(T[c + 1][r]);
    o.z = f2h(T[c + 2][r]); o.w = f2h(T[c + 3][r]);
    *(ushort4*)&D[(size_t)(n0 + r) * DMODEL + k0 + c] = o;
}

// ---------------------------------------------------------------------------
// Mask pre-pass: em = fp16(exp(mask)), permuted to the S^T C-layout order.
// Element (q,k): kt=k>>6, kl=k&63 = 32*mt + 8*g + 4*hl + r
//   -> em[((kt*SEQ+q)*64) + hl*32 + mt*16 + g*4 + r]
// ---------------------------------------------------------------------------
__global__ __launch_bounds__(256) void prep_mask(
    const float* __restrict__ mask, unsigned short* __restrict__ mp)
{
    int i = blockIdx.x * 256 + threadIdx.x;     // float4 index
    int k = (i * 4) & (SEQ - 1);
    int q = (i * 4) >> 11;
    float4 v = ((const float4*)mask)[i];
    int kt = k >> 6, kl = k & 63;
    int mt = kl >> 5, g = (kl >> 3) & 3, hl = (kl >> 2) & 1;
    size_t base = ((size_t)kt * SEQ + q) * 64 + hl * 32 + mt * 16 + g * 4;
    ushort4 o;
    o.x = f2h(__builtin_amdgcn_exp2f(v.x * LOG2E));
    o.y = f2h(__builtin_amdgcn_exp2f(v.y * LOG2E));
    o.z = f2h(__builtin_amdgcn_exp2f(v.z * LOG2E));
    o.w = f2h(__builtin_amdgcn_exp2f(v.w * LOG2E));
    *(ushort4*)&mp[base] = o;
}

// ---------------------------------------------------------------------------
// Per-head transpose of the V projection (f16 bits, dtype-agnostic):
// vb[b*SEQ+key][h*64+dv] -> vT[((b*8+h)*64+dv)*SEQ + key]
// ---------------------------------------------------------------------------
__global__ __launch_bounds__(256) void transpose_v(
    const unsigned short* __restrict__ vb, unsigned short* __restrict__ vT)
{
    const int t = threadIdx.x;
    const int key0 = blockIdx.x * 64;
    const int bh = blockIdx.y, b = bh >> 3, h = bh & 7;
    #pragma unroll
    for (int p = 0; p < 2; p++) {
        int cid = p * 256 + t;
        int dv = cid >> 3, kch = cid & 7;
        unsigned short tmp[8];
        #pragma unroll
        for (int j = 0; j < 8; j++)
            tmp[j] = vb[(size_t)(b * SEQ + key0 + kch * 8 + j) * DMODEL + h * HDIM + dv];
        uint4 o;
        o.x = tmp[0] | ((unsigned)tmp[1] << 16);
        o.y = tmp[2] | ((unsigned)tmp[3] << 16);
        o.z = tmp[4] | ((unsigned)tmp[5] << 16);
        o.w = tmp[6] | ((unsigned)tmp[7] << 16);
        *(uint4*)&vT[(size_t)((b * NHEAD + h) * HDIM + dv) * SEQ + key0 + kch * 8] = o;
    }
}

// ---------------------------------------------------------------------------
// GEMM core: C[..][512] = A[..][512] @ Wt[512][512]^T + bias (Wt is [n][k]).
// 128x128 tile, BK=32, 256 thr = 4 waves, wave = 64m x 64n (4x4 MFMA 16x16x32).
// A_FP32: fused fp32->f16 cast in staging; else async global_load_lds f16.
// ---------------------------------------------------------------------------
template <int A_FP32, int OUT_F16>
static __device__ inline void gemm_core(
    const void* __restrict__ Ap, const unsigned short* __restrict__ Bt,
    const float* __restrict__ bias, void* __restrict__ Cout, float oscale,
    int bm, int bn)
{
    __shared__ __align__(16) unsigned short As[128 * 32];
    __shared__ __align__(16) unsigned short Bs[128 * 32];

    const int t = threadIdx.x;
    const int lane = t & 63, w = t >> 6;
    const int wm = w >> 1, wn = w & 1;
    const int c = lane & 15, quad = lane >> 4;

    f32x4 acc[4][4] = {};

    for (int k0 = 0; k0 < DMODEL; k0 += 32) {
        if (A_FP32) {
            const float* Af = (const float*)Ap;
            #pragma unroll
            for (int p = 0; p < 4; p++) {
                int cid = p * 256 + t;
                int row = cid >> 3, fc = cid & 7;
                float4 av = *(const float4*)&Af[(size_t)(bm + row) * DMODEL + k0 + fc * 4];
                U1H2 lo, hi;
                lo.h = pkrtz(av.x, av.y);
                hi.h = pkrtz(av.z, av.w);
                uint2 st = make_uint2(lo.u, hi.u);
                *(uint2*)&As[row * 32 + fc * 4] = st;
            }
        } else {
            const unsigned short* Ab = (const unsigned short*)Ap;
            #pragma unroll
            for (int i = 0; i < 2; i++) {
                int row = 32 * w + 16 * i + (lane >> 2);
                const unsigned short* gp = Ab + (size_t)(bm + row) * DMODEL + k0 + (lane & 3) * 8;
                async_cp16(gp, &As[(32 * w + 16 * i) * 32]);
            }
        }
        #pragma unroll
        for (int i = 0; i < 2; i++) {
            int row = 32 * w + 16 * i + (lane >> 2);
            const unsigned short* gp = Bt + (size_t)(bn + row) * DMODEL + k0 + (lane & 3) * 8;
            async_cp16(gp, &Bs[(32 * w + 16 * i) * 32]);
        }
        __syncthreads();

        U4H af[4], bf[4];
        #pragma unroll
        for (int mt = 0; mt < 4; mt++)
            af[mt].u = *(const uint4*)&As[(wm * 64 + mt * 16 + c) * 32 + quad * 8];
        #pragma unroll
        for (int nt = 0; nt < 4; nt++)
            bf[nt].u = *(const uint4*)&Bs[(wn * 64 + nt * 16 + c) * 32 + quad * 8];
        #pragma unroll
        for (int mt = 0; mt < 4; mt++)
            #pragma unroll
            for (int nt = 0; nt < 4; nt++)
                acc[mt][nt] = __builtin_amdgcn_mfma_f32_16x16x32_f16(
                    af[mt].h, bf[nt].h, acc[mt][nt], 0, 0, 0);
        __syncthreads();
    }

    #pragma unroll
    for (int nt = 0; nt < 4; nt++) {
        int ng = bn + wn * 64 + nt * 16 + c;
        float bv = bias[ng];
        #pragma unroll
        for (int mt = 0; mt < 4; mt++) {
            #pragma unroll
            for (int r = 0; r < 4; r++) {
                int mg = bm + wm * 64 + mt * 16 + quad * 4 + r;
                float v = (acc[mt][nt][r] + bv) * oscale;
                if (OUT_F16)
                    ((unsigned short*)Cout)[(size_t)mg * DMODEL + ng] = f2h(v);
                else
                    ((float*)Cout)[(size_t)mg * DMODEL + ng] = v;
            }
        }
    }
}

struct QKVArgs {
    const float *A0, *A1, *A2;
    const unsigned short *W0, *W1, *W2;
    const float *b0, *b1, *b2;
    unsigned short *o0, *o1, *o2;
};

__global__ __launch_bounds__(256) void gemm_qkv(QKVArgs a) {
    const float* A; const unsigned short* W; const float* bias;
    unsigned short* out; float sc;
    switch (blockIdx.z) {
        case 0: A = a.A0; W = a.W0; bias = a.b0; out = a.o0; sc = QSCALE; break;
        case 1: A = a.A1; W = a.W1; bias = a.b1; out = a.o1; sc = 1.0f;  break;
        default: A = a.A2; W = a.W2; bias = a.b2; out = a.o2; sc = 1.0f; break;
    }
    gemm_core<1, 1>(A, W, bias, out, sc, blockIdx.y * 128, blockIdx.x * 128);
}

__global__ __launch_bounds__(256) void gemm_fin(
    const unsigned short* __restrict__ A, const unsigned short* __restrict__ W,
    const float* __restrict__ bias, float* __restrict__ C) {
    gemm_core<0, 0>(A, W, bias, C, 1.0f, blockIdx.y * 128, blockIdx.x * 128);
}

// ---------------------------------------------------------------------------
// Flash attention, 32x32x16 f16 MFMA, S^T trick, no-max softmax (p=exp2(S)*em).
// Block = 256 threads (4 waves) x 128 q rows; wave w owns q = q0+32w+(lane&31).
// __launch_bounds__(256,2): VGPR cap 256 -> live set ~180 fits, NO SPILLS
// (round-5's (128) default capped at 96 VGPR -> 370 MB scratch traffic).
// LDS planes padded to 65 rows (stride 1040B): staging writes and frag reads
// both conflict-free per 8-lane b128 phase (round-5 measured 0 conflicts).
// Register prefetch of next K/V tile (2+2 uint4/thread) hides global latency.
// ---------------------------------------------------------------------------
__global__ __launch_bounds__(256, 2) void attn4(
    const unsigned short* __restrict__ qb, const unsigned short* __restrict__ kb,
    const unsigned short* __restrict__ vT, const unsigned short* __restrict__ emp,
    unsigned short* __restrict__ X)
{
    __shared__ __align__(16) unsigned short Ks[8 * 65 * 8];
    __shared__ __align__(16) unsigned short Vs[8 * 65 * 8];

    const int t = threadIdx.x;            // 0..255
    const int lane = t & 63, w = t >> 6;  // 4 waves
    const int c32 = lane & 31, hl = lane >> 5;
    const int bh = blockIdx.x, b = bh >> 3, head = bh & 7;
    const int q0 = blockIdx.y * 128;
    const int qg = q0 + w * 32 + c32;

    // hoisted Q B-frags (q pre-scaled by 0.125*log2e in projection)
    const unsigned short* qrow = qb + ((size_t)b * SEQ + qg) * DMODEL + head * HDIM;
    U4H Qf[4];
    #pragma unroll
    for (int s = 0; s < 4; s++)
        Qf[s].u = *(const uint4*)&qrow[s * 16 + hl * 8];

    const unsigned short* kgb = kb + (size_t)b * SEQ * DMODEL + head * HDIM;
    const unsigned short* vgb = vT + (size_t)bh * HDIM * SEQ;

    const int r8p = t >> 3;               // 0..31; +32p covers 64 rows
    const int chp = t & 7;                // feature/key chunk for staging

    uint4 kreg[2], vreg[2];
    #pragma unroll
    for (int p = 0; p < 2; p++) {         // prefetch tile 0
        int r8 = p * 32 + r8p;
        kreg[p] = *(const uint4*)&kgb[(size_t)r8 * DMODEL + chp * 8];
        vreg[p] = *(const uint4*)&vgb[(size_t)r8 * SEQ + 0 + chp * 8];
    }

    f32x16 O0 = {}, O1 = {};
    float lsum = 0.f;

    for (int kt = 0; kt < SEQ / 64; kt++) {
        __syncthreads();                  // prev iter's LDS reads done
        #pragma unroll
        for (int p = 0; p < 2; p++) {
            int r8 = p * 32 + r8p;
            *(uint4*)&Ks[(chp * 65 + r8) * 8] = kreg[p];
            *(uint4*)&Vs[(chp * 65 + r8) * 8] = vreg[p];
        }
        __syncthreads();                  // tiles staged

        if (kt + 1 < SEQ / 64) {          // prefetch next tile (hidden by compute)
            int k0n = (kt + 1) * 64;
            #pragma unroll
            for (int p = 0; p < 2; p++) {
                int r8 = p * 32 + r8p;
                kreg[p] = *(const uint4*)&kgb[(size_t)(k0n + r8) * DMODEL + chp * 8];
                vreg[p] = *(const uint4*)&vgb[(size_t)r8 * SEQ + k0n + chp * 8];
            }
        }

        // em loads (f16, permuted layout)
        const unsigned short* mrow = emp + ((size_t)kt * SEQ + qg) * 64 + hl * 32;
        U4H e0, e1, e2, e3;
        e0.u = *(const uint4*)&mrow[0];
        e1.u = *(const uint4*)&mrow[8];
        e2.u = *(const uint4*)&mrow[16];
        e3.u = *(const uint4*)&mrow[24];

        // ---- S^T = K.Q^T : 2 key-tiles x 4 feature-steps ----
        f32x16 S0 = {}, S1 = {};
        #pragma unroll
        for (int s = 0; s < 4; s++) {
            int fc = 2 * s + hl;
            U4H ka0, ka1;
            ka0.u = *(const uint4*)&Ks[(fc * 65 + c32) * 8];
            ka1.u = *(const uint4*)&Ks[(fc * 65 + 32 + c32) * 8];
            S0 = __builtin_amdgcn_mfma_f32_32x32x16_f16(ka0.h, Qf[s].h, S0, 0, 0, 0);
            S1 = __builtin_amdgcn_mfma_f32_32x32x16_f16(ka1.h, Qf[s].h, S1, 0, 0, 0);
        }

        // ---- softmax: p = exp2(S) * em, f16 pack, l-accumulate ----
        unsigned int Pf[4][4];
        #pragma unroll
        for (int mt = 0; mt < 2; mt++) {
            f32x16 S = mt ? S1 : S0;
            h16x8 ea = (mt ? e2 : e0).h;
            h16x8 eb = (mt ? e3 : e1).h;
            unsigned int u[4][2];
            #pragma unroll
            for (int jj = 0; jj < 8; jj++) {
                _Float16 exl = (jj < 4) ? ea[2 * jj]     : eb[2 * jj - 8];
                _Float16 exh = (jj < 4) ? ea[2 * jj + 1] : eb[2 * jj - 7];
                h16x2 ex = {exl, exh};
                h16x2 pk = pkrtz(__builtin_amdgcn_exp2f(S[2 * jj]),
                                 __builtin_amdgcn_exp2f(S[2 * jj + 1]));
                h16x2 pp = pk * ex;
                lsum += (float)pp[0] + (float)pp[1];
                u[jj >> 1][jj & 1] = __builtin_bit_cast(unsigned int, pp);
            }
            // half-wave block exchange (C-layout -> PV B-operand layout)
            unsigned int sA0 = hl ? u[0][0] : u[1][0];
            unsigned int sA1 = hl ? u[0][1] : u[1][1];
            unsigned int sB0 = hl ? u[2][0] : u[3][0];
            unsigned int sB1 = hl ? u[2][1] : u[3][1];
            unsigned int rA0 = (unsigned)__shfl_xor((int)sA0, 32, 64);
            unsigned int rA1 = (unsigned)__shfl_xor((int)sA1, 32, 64);
            unsigned int rB0 = (unsigned)__shfl_xor((int)sB0, 32, 64);
            unsigned int rB1 = (unsigned)__shfl_xor((int)sB1, 32, 64);
            Pf[2 * mt + 0][0] = hl ? rA0 : u[0][0];
            Pf[2 * mt + 0][1] = hl ? rA1 : u[0][1];
            Pf[2 * mt + 0][2] = hl ? u[1][0] : rA0;
            Pf[2 * mt + 0][3] = hl ? u[1][1] : rA1;
            Pf[2 * mt + 1][0] = hl ? rB0 : u[2][0];
            Pf[2 * mt + 1][1] = hl ? rB1 : u[2][1];
            Pf[2 * mt + 1][2] = hl ? u[3][0] : rB0;
            Pf[2 * mt + 1][3] = hl ? u[3][1] : rB1;
        }

        // ---- O^T += V^T . P : 2 dv-tiles x 4 key-steps ----
        #pragma unroll
        for (int s = 0; s < 4; s++) {
            int kc = 2 * s + hl;
            U4H va0, va1, pu;
            va0.u = *(const uint4*)&Vs[(kc * 65 + c32) * 8];
            va1.u = *(const uint4*)&Vs[(kc * 65 + 32 + c32) * 8];
            pu.u = make_uint4(Pf[s][0], Pf[s][1], Pf[s][2], Pf[s][3]);
            O0 = __builtin_amdgcn_mfma_f32_32x32x16_f16(va0.h, pu.h, O0, 0, 0, 0);
            O1 = __builtin_amdgcn_mfma_f32_32x32x16_f16(va1.h, pu.h, O1, 0, 0, 0);
        }
    }

    // ---- epilogue: combine lane-halves' l, scale, f16 store (scrambled) ----
    lsum += __shfl_xor(lsum, 32, 64);
    float inv = 1.0f / lsum;
    unsigned short* xrow = X + (((size_t)head * SEQ + qg) * BATCH + b) * HDIM;
    #pragma unroll
    for (int mt = 0; mt < 2; mt++) {
        f32x16 Ov = mt ? O1 : O0;
        #pragma unroll
        for (int g = 0; g < 4; g++) {
            U1H2 lo, hi;
            lo.h = pkrtz(Ov[g * 4 + 0] * inv, Ov[g * 4 + 1] * inv);
            hi.h = pkrtz(Ov[g * 4 + 2] * inv, Ov[g * 4 + 3] * inv);
            uint2 st = make_uint2(lo.u, hi.u);
            *(uint2*)&xrow[mt * 32 + 8 * g + 4 * hl] = st;
        }
    }
}

// ---------------------------------------------------------------------------
extern "C" void kernel_launch(void* const* d_in, const int* in_sizes, int n_in,
                              void* d_out, int out_size, void* d_ws, size_t ws_size,
                              hipStream_t stream) {
    const float* query = (const float*)d_in[0];
    const float* key_  = (const float*)d_in[1];
    const float* value = (const float*)d_in[2];
    const float* mask  = (const float*)d_in[3];
    const float* Wq = (const float*)d_in[4];
    const float* bq = (const float*)d_in[5];
    const float* Wk = (const float*)d_in[6];
    const float* bk = (const float*)d_in[7];
    const float* Wv = (const float*)d_in[8];
    const float* bv = (const float*)d_in[9];
    const float* Wo = (const float*)d_in[10];
    const float* bo = (const float*)d_in[11];
    float* out = (float*)d_out;

    const size_t NP = (size_t)BATCH * SEQ * DMODEL;   // 4194304
    unsigned short* ws   = (unsigned short*)d_ws;
    unsigned short* qb16 = ws;
    unsigned short* kb16 = qb16 + NP;
    unsigned short* vb16 = kb16 + NP;
    unsigned short* vT16 = vb16 + NP;
    unsigned short* xb16 = vT16 + NP;
    unsigned short* em16 = xb16 + NP;                 // SEQ*SEQ f16
    unsigned short* WqT  = em16 + (size_t)SEQ * SEQ;
    unsigned short* WkT  = WqT + DMODEL * DMODEL;
    unsigned short* WvT  = WkT + DMODEL * DMODEL;
    unsigned short* WoT  = WvT + DMODEL * DMODEL;
    // total ws use ~52 MB

    transpose_cast_w<<<dim3(16, 16, 4), 256, 0, stream>>>(
        Wq, Wk, Wv, Wo, WqT, WkT, WvT, WoT);
    prep_mask<<<dim3(SEQ * SEQ / 4 / 256), 256, 0, stream>>>(mask, em16);

    QKVArgs qa;
    qa.A0 = query; qa.A1 = key_; qa.A2 = value;
    qa.W0 = WqT;   qa.W1 = WkT;  qa.W2 = WvT;
    qa.b0 = bq;    qa.b1 = bk;   qa.b2 = bv;
    qa.o0 = qb16;  qa.o1 = kb16; qa.o2 = vb16;
    gemm_qkv<<<dim3(DMODEL / 128, BATCH * SEQ / 128, 3), 256, 0, stream>>>(qa);

    transpose_v<<<dim3(SEQ / 64, BATCH * NHEAD), 256, 0, stream>>>(vb16, vT16);

    attn4<<<dim3(BATCH * NHEAD, SEQ / 128), 256, 0, stream>>>(
        qb16, kb16, vT16, em16, xb16);

    gemm_fin<<<dim3(DMODEL / 128, BATCH * SEQ / 128), 256, 0, stream>>>(
        xb16, WoT, bo, out);
}

// Round 7
// 253.117 us; speedup vs baseline: 1.4382x; 1.0472x over previous
//
#include <hip/hip_runtime.h>

#define SEQ    2048
#define DMODEL 512
#define NHEAD  8
#define HDIM   64
#define BATCH  4
#define NROWS  65536          // H*SEQ*BATCH scrambled q-rows
#define KSPLIT 2

#define LOG2E  1.4426950408889634f
#define QSCALE 0.18033688011112042f   // 0.125 * log2(e), folded into Q proj

typedef float f32x4  __attribute__((ext_vector_type(4)));
typedef float f32x16 __attribute__((ext_vector_type(16)));
typedef _Float16 h16x8 __attribute__((ext_vector_type(8)));
typedef _Float16 h16x2 __attribute__((ext_vector_type(2)));

union U4H { uint4 u; h16x8 h; };
union U1H2 { unsigned int u; h16x2 h; };

static __device__ inline h16x2 pkrtz(float a, float b) {
    return __builtin_bit_cast(h16x2, __builtin_amdgcn_cvt_pkrtz(a, b));
}
static __device__ inline unsigned short f2h(float x) {
    _Float16 h = (_Float16)x;
    return __builtin_bit_cast(unsigned short, h);
}
// async 16B/lane global->LDS copy (lds base must be wave-uniform)
static __device__ inline void async_cp16(const void* g, void* l) {
    __builtin_amdgcn_global_load_lds(
        (const __attribute__((address_space(1))) unsigned int*)g,
        (__attribute__((address_space(3))) unsigned int*)l,
        16, 0, 0);
}

// ---------------------------------------------------------------------------
// Transpose-cast the four 512x512 weight matrices: W[k][n] -> Wt[n][k] fp16
// ---------------------------------------------------------------------------
__global__ __launch_bounds__(256) void transpose_cast_w(
    const float* __restrict__ s0, const float* __restrict__ s1,
    const float* __restrict__ s2, const float* __restrict__ s3,
    unsigned short* __restrict__ d0, unsigned short* __restrict__ d1,
    unsigned short* __restrict__ d2, unsigned short* __restrict__ d3)
{
    const float* S; unsigned short* D;
    switch (blockIdx.z) {
        case 0: S = s0; D = d0; break;
        case 1: S = s1; D = d1; break;
        case 2: S = s2; D = d2; break;
        default: S = s3; D = d3; break;
    }
    __shared__ float T[32][33];
    const int t = threadIdx.x;
    const int r = t >> 3, c = (t & 7) * 4;
    const int k0 = blockIdx.x * 32, n0 = blockIdx.y * 32;
    float4 v = *(const float4*)&S[(size_t)(k0 + r) * DMODEL + n0 + c];
    T[r][c] = v.x; T[r][c + 1] = v.y; T[r][c + 2] = v.z; T[r][c + 3] = v.w;
    __syncthreads();
    ushort4 o;
    o.x = f2h(T[c + 0][r]); o.y = f2h(T[c + 1][r]);
    o.z = f2h(T[c + 2][r]); o.w = f2h(T[c + 3][r]);
    *(ushort4*)&D[(size_t)(n0 + r) * DMODEL + k0 + c] = o;
}

// ---------------------------------------------------------------------------
// Mask pre-pass: em = fp16(exp(mask)), permuted to the S^T C-layout order.
// Element (q,k): kt=k>>6, kl=k&63 = 32*mt + 8*g + 4*hl + r
//   -> em[((kt*SEQ+q)*64) + hl*32 + mt*16 + g*4 + r]
// ---------------------------------------------------------------------------
__global__ __launch_bounds__(256) void prep_mask(
    const float* __restrict__ mask, unsigned short* __restrict__ mp)
{
    int i = blockIdx.x * 256 + threadIdx.x;     // float4 index
    int k = (i * 4) & (SEQ - 1);
    int q = (i * 4) >> 11;
    float4 v = ((const float4*)mask)[i];
    int kt = k >> 6, kl = k & 63;
    int mt = kl >> 5, g = (kl >> 3) & 3, hl = (kl >> 2) & 1;
    size_t base = ((size_t)kt * SEQ + q) * 64 + hl * 32 + mt * 16 + g * 4;
    ushort4 o;
    o.x = f2h(__builtin_amdgcn_exp2f(v.x * LOG2E));
    o.y = f2h(__builtin_amdgcn_exp2f(v.y * LOG2E));
    o.z = f2h(__builtin_amdgcn_exp2f(v.z * LOG2E));
    o.w = f2h(__builtin_amdgcn_exp2f(v.w * LOG2E));
    *(ushort4*)&mp[base] = o;
}

// ---------------------------------------------------------------------------
// GEMM core: C[..][512] = A[..][512] @ Wt[512][512]^T + bias (Wt is [n][k]).
// 128x128 tile, BK=32, 256 thr = 4 waves, wave = 64m x 64n (4x4 MFMA 16x16x32).
// A_FP32: fused fp32->f16 cast in staging; else async global_load_lds f16.
// EPI: 0 = f32 row-major, 1 = f16 row-major, 2 = f16 transposed per-head to
//      vT[((b*8+h)*64+dv)*SEQ + key]  (fuses the old transpose_v kernel).
// ---------------------------------------------------------------------------
template <int A_FP32, int EPI>
static __device__ inline void gemm_core(
    const void* __restrict__ Ap, const unsigned short* __restrict__ Bt,
    const float* __restrict__ bias, void* __restrict__ Cout, float oscale,
    int bm, int bn)
{
    __shared__ __align__(16) unsigned short As[128 * 32];
    __shared__ __align__(16) unsigned short Bs[128 * 32];

    const int t = threadIdx.x;
    const int lane = t & 63, w = t >> 6;
    const int wm = w >> 1, wn = w & 1;
    const int c = lane & 15, quad = lane >> 4;

    f32x4 acc[4][4] = {};

    for (int k0 = 0; k0 < DMODEL; k0 += 32) {
        if (A_FP32) {
            const float* Af = (const float*)Ap;
            #pragma unroll
            for (int p = 0; p < 4; p++) {
                int cid = p * 256 + t;
                int row = cid >> 3, fc = cid & 7;
                float4 av = *(const float4*)&Af[(size_t)(bm + row) * DMODEL + k0 + fc * 4];
                U1H2 lo, hi;
                lo.h = pkrtz(av.x, av.y);
                hi.h = pkrtz(av.z, av.w);
                uint2 st = make_uint2(lo.u, hi.u);
                *(uint2*)&As[row * 32 + fc * 4] = st;
            }
        } else {
            const unsigned short* Ab = (const unsigned short*)Ap;
            #pragma unroll
            for (int i = 0; i < 2; i++) {
                int row = 32 * w + 16 * i + (lane >> 2);
                const unsigned short* gp = Ab + (size_t)(bm + row) * DMODEL + k0 + (lane & 3) * 8;
                async_cp16(gp, &As[(32 * w + 16 * i) * 32]);
            }
        }
        #pragma unroll
        for (int i = 0; i < 2; i++) {
            int row = 32 * w + 16 * i + (lane >> 2);
            const unsigned short* gp = Bt + (size_t)(bn + row) * DMODEL + k0 + (lane & 3) * 8;
            async_cp16(gp, &Bs[(32 * w + 16 * i) * 32]);
        }
        __syncthreads();

        U4H af[4], bf[4];
        #pragma unroll
        for (int mt = 0; mt < 4; mt++)
            af[mt].u = *(const uint4*)&As[(wm * 64 + mt * 16 + c) * 32 + quad * 8];
        #pragma unroll
        for (int nt = 0; nt < 4; nt++)
            bf[nt].u = *(const uint4*)&Bs[(wn * 64 + nt * 16 + c) * 32 + quad * 8];
        #pragma unroll
        for (int mt = 0; mt < 4; mt++)
            #pragma unroll
            for (int nt = 0; nt < 4; nt++)
                acc[mt][nt] = __builtin_amdgcn_mfma_f32_16x16x32_f16(
                    af[mt].h, bf[nt].h, acc[mt][nt], 0, 0, 0);
        __syncthreads();
    }

    if (EPI == 2) {
        // transposed per-head write: 4 consecutive keys per acc reg group
        #pragma unroll
        for (int nt = 0; nt < 4; nt++) {
            int ng = bn + wn * 64 + nt * 16 + c;
            int h = ng >> 6, dv = ng & 63;
            float bv = bias[ng];
            #pragma unroll
            for (int mt = 0; mt < 4; mt++) {
                int mg0 = bm + wm * 64 + mt * 16 + quad * 4;
                int bb = mg0 >> 11, key0 = mg0 & (SEQ - 1);
                U1H2 lo, hi;
                lo.h = pkrtz(acc[mt][nt][0] + bv, acc[mt][nt][1] + bv);
                hi.h = pkrtz(acc[mt][nt][2] + bv, acc[mt][nt][3] + bv);
                *(uint2*)&((unsigned short*)Cout)[
                    ((size_t)(bb * NHEAD + h) * HDIM + dv) * SEQ + key0] =
                    make_uint2(lo.u, hi.u);
            }
        }
        return;
    }
    #pragma unroll
    for (int nt = 0; nt < 4; nt++) {
        int ng = bn + wn * 64 + nt * 16 + c;
        float bv = bias[ng];
        #pragma unroll
        for (int mt = 0; mt < 4; mt++) {
            #pragma unroll
            for (int r = 0; r < 4; r++) {
                int mg = bm + wm * 64 + mt * 16 + quad * 4 + r;
                float v = (acc[mt][nt][r] + bv) * oscale;
                if (EPI == 1)
                    ((unsigned short*)Cout)[(size_t)mg * DMODEL + ng] = f2h(v);
                else
                    ((float*)Cout)[(size_t)mg * DMODEL + ng] = v;
            }
        }
    }
}

struct QKVArgs {
    const float *A0, *A1, *A2;
    const unsigned short *W0, *W1, *W2;
    const float *b0, *b1, *b2;
    unsigned short *o0, *o1, *o2;
};

__global__ __launch_bounds__(256) void gemm_qkv(QKVArgs a) {
    if (blockIdx.z == 2)
        gemm_core<1, 2>(a.A2, a.W2, a.b2, a.o2, 1.0f, blockIdx.y * 128, blockIdx.x * 128);
    else if (blockIdx.z == 1)
        gemm_core<1, 1>(a.A1, a.W1, a.b1, a.o1, 1.0f, blockIdx.y * 128, blockIdx.x * 128);
    else
        gemm_core<1, 1>(a.A0, a.W0, a.b0, a.o0, QSCALE, blockIdx.y * 128, blockIdx.x * 128);
}

__global__ __launch_bounds__(256) void gemm_fin(
    const unsigned short* __restrict__ A, const unsigned short* __restrict__ W,
    const float* __restrict__ bias, float* __restrict__ C) {
    gemm_core<0, 0>(A, W, bias, C, 1.0f, blockIdx.y * 128, blockIdx.x * 128);
}

// ---------------------------------------------------------------------------
// Flash attention, 32x32x16 f16 MFMA, S^T trick, no-max softmax, K-SPLIT 2.
// Block = 4 waves x 128 q rows x 1024 keys; wave w owns q = q0+32w+(lane&31).
// Staging via global_load_lds double-buffer, ONE barrier per K-tile.
// XOR swizzle lives on the GLOBAL address (lane loads chunk (lane&7)^(row&7));
// physical LDS [row][slot] then makes all b128 frag reads conflict-free
// (slot = chunk ^ (row&7) distinct across each 8-lane phase).
// Partials: unnormalized O^T as f16 + lsum f32; combined by combine_attn.
// ---------------------------------------------------------------------------
__global__ __launch_bounds__(256, 3) void attn5(
    const unsigned short* __restrict__ qb, const unsigned short* __restrict__ kb,
    const unsigned short* __restrict__ vT, const unsigned short* __restrict__ emp,
    unsigned short* __restrict__ Xp, float* __restrict__ Lp)
{
    __shared__ __align__(16) unsigned short Ks[2][64 * 64];
    __shared__ __align__(16) unsigned short Vs[2][64 * 64];

    const int t = threadIdx.x;            // 0..255
    const int lane = t & 63, w = t >> 6;  // 4 waves
    const int c32 = lane & 31, hl = lane >> 5;
    const int bh = blockIdx.x, b = bh >> 3, head = bh & 7;
    const int q0 = blockIdx.y * 128;
    const int split = blockIdx.z;         // keys [split*1024, split*1024+1024)
    const int qg = q0 + w * 32 + c32;

    // hoisted Q B-frags (q pre-scaled by 0.125*log2e in projection)
    const unsigned short* qrow = qb + ((size_t)b * SEQ + qg) * DMODEL + head * HDIM;
    U4H Qf[4];
    #pragma unroll
    for (int s = 0; s < 4; s++)
        Qf[s].u = *(const uint4*)&qrow[s * 16 + hl * 8];

    const unsigned short* kgb = kb + (size_t)b * SEQ * DMODEL + head * HDIM
                              + (size_t)split * 1024 * DMODEL;
    const unsigned short* vgb = vT + (size_t)bh * HDIM * SEQ + split * 1024;

    // staging lane mapping: row-in-chunk = lane>>3, swizzled global chunk
    const int srow = lane >> 3;           // 0..7
    const int sch  = (lane & 7) ^ srow;   // logical feature/key chunk

    // issue tile 0 into buffer 0
    {
        #pragma unroll
        for (int i = 0; i < 2; i++) {
            int row = w * 16 + i * 8 + srow;
            async_cp16(&kgb[(size_t)row * DMODEL + sch * 8], &Ks[0][(w * 16 + i * 8) * 64]);
            async_cp16(&vgb[(size_t)row * SEQ + sch * 8],    &Vs[0][(w * 16 + i * 8) * 64]);
        }
    }

    f32x16 O0 = {}, O1 = {};
    float lsum = 0.f;

    for (int kt = 0; kt < 1024 / 64; kt++) {
        const int p = kt & 1;
        __syncthreads();                  // buf[p] staged; buf[p^1] reads done

        // em loads FIRST (so their vmcnt wait doesn't drain the async stage)
        const int ktg = split * 16 + kt;
        const unsigned short* mrow = emp + ((size_t)ktg * SEQ + qg) * 64 + hl * 32;
        U4H e0, e1, e2, e3;
        e0.u = *(const uint4*)&mrow[0];
        e1.u = *(const uint4*)&mrow[8];
        e2.u = *(const uint4*)&mrow[16];
        e3.u = *(const uint4*)&mrow[24];

        // async stage tile kt+1 into the other buffer (in flight during compute)
        if (kt + 1 < 1024 / 64) {
            int k0n = (kt + 1) * 64;
            #pragma unroll
            for (int i = 0; i < 2; i++) {
                int row = w * 16 + i * 8 + srow;
                async_cp16(&kgb[(size_t)(k0n + row) * DMODEL + sch * 8],
                           &Ks[p ^ 1][(w * 16 + i * 8) * 64]);
                async_cp16(&vgb[(size_t)row * SEQ + k0n + sch * 8],
                           &Vs[p ^ 1][(w * 16 + i * 8) * 64]);
            }
        }

        const unsigned short* Kp = Ks[p];
        const unsigned short* Vp = Vs[p];

        // ---- S^T = K.Q^T : 2 key-tiles x 4 feature-steps ----
        f32x16 S0 = {}, S1 = {};
        #pragma unroll
        for (int s = 0; s < 4; s++) {
            int fc = 2 * s + hl;
            int sl = (fc ^ (c32 & 7)) * 8;
            U4H ka0, ka1;
            ka0.u = *(const uint4*)&Kp[c32 * 64 + sl];
            ka1.u = *(const uint4*)&Kp[(32 + c32) * 64 + sl];
            S0 = __builtin_amdgcn_mfma_f32_32x32x16_f16(ka0.h, Qf[s].h, S0, 0, 0, 0);
            S1 = __builtin_amdgcn_mfma_f32_32x32x16_f16(ka1.h, Qf[s].h, S1, 0, 0, 0);
        }

        // ---- softmax: p = exp2(S) * em, f16 pack, l-accumulate ----
        unsigned int Pf[4][4];
        #pragma unroll
        for (int mt = 0; mt < 2; mt++) {
            f32x16 S = mt ? S1 : S0;
            h16x8 ea = (mt ? e2 : e0).h;
            h16x8 eb = (mt ? e3 : e1).h;
            unsigned int u[4][2];
            #pragma unroll
            for (int jj = 0; jj < 8; jj++) {
                _Float16 exl = (jj < 4) ? ea[2 * jj]     : eb[2 * jj - 8];
                _Float16 exh = (jj < 4) ? ea[2 * jj + 1] : eb[2 * jj - 7];
                h16x2 ex = {exl, exh};
                h16x2 pk = pkrtz(__builtin_amdgcn_exp2f(S[2 * jj]),
                                 __builtin_amdgcn_exp2f(S[2 * jj + 1]));
                h16x2 pp = pk * ex;
                lsum += (float)pp[0] + (float)pp[1];
                u[jj >> 1][jj & 1] = __builtin_bit_cast(unsigned int, pp);
            }
            // half-wave block exchange (C-layout -> PV B-operand layout)
            unsigned int sA0 = hl ? u[0][0] : u[1][0];
            unsigned int sA1 = hl ? u[0][1] : u[1][1];
            unsigned int sB0 = hl ? u[2][0] : u[3][0];
            unsigned int sB1 = hl ? u[2][1] : u[3][1];
            unsigned int rA0 = (unsigned)__shfl_xor((int)sA0, 32, 64);
            unsigned int rA1 = (unsigned)__shfl_xor((int)sA1, 32, 64);
            unsigned int rB0 = (unsigned)__shfl_xor((int)sB0, 32, 64);
            unsigned int rB1 = (unsigned)__shfl_xor((int)sB1, 32, 64);
            Pf[2 * mt + 0][0] = hl ? rA0 : u[0][0];
            Pf[2 * mt + 0][1] = hl ? rA1 : u[0][1];
            Pf[2 * mt + 0][2] = hl ? u[1][0] : rA0;
            Pf[2 * mt + 0][3] = hl ? u[1][1] : rA1;
            Pf[2 * mt + 1][0] = hl ? rB0 : u[2][0];
            Pf[2 * mt + 1][1] = hl ? rB1 : u[2][1];
            Pf[2 * mt + 1][2] = hl ? u[3][0] : rB0;
            Pf[2 * mt + 1][3] = hl ? u[3][1] : rB1;
        }

        // ---- O^T += V^T . P : 2 dv-tiles x 4 key-steps ----
        #pragma unroll
        for (int s = 0; s < 4; s++) {
            int kc = 2 * s + hl;
            int sl = (kc ^ (c32 & 7)) * 8;
            U4H va0, va1, pu;
            va0.u = *(const uint4*)&Vp[c32 * 64 + sl];
            va1.u = *(const uint4*)&Vp[(32 + c32) * 64 + sl];
            pu.u = make_uint4(Pf[s][0], Pf[s][1], Pf[s][2], Pf[s][3]);
            O0 = __builtin_amdgcn_mfma_f32_32x32x16_f16(va0.h, pu.h, O0, 0, 0, 0);
            O1 = __builtin_amdgcn_mfma_f32_32x32x16_f16(va1.h, pu.h, O1, 0, 0, 0);
        }
    }

    // ---- epilogue: combine lane-halves' l, store UNNORMALIZED f16 partial ----
    lsum += __shfl_xor(lsum, 32, 64);
    const size_t j = ((size_t)head * SEQ + qg) * BATCH + b;
    unsigned short* xr = Xp + ((size_t)split * NROWS + j) * HDIM;
    #pragma unroll
    for (int mt = 0; mt < 2; mt++) {
        f32x16 Ov = mt ? O1 : O0;
        #pragma unroll
        for (int g = 0; g < 4; g++) {
            U1H2 lo, hi;
            lo.h = pkrtz(Ov[g * 4 + 0], Ov[g * 4 + 1]);
            hi.h = pkrtz(Ov[g * 4 + 2], Ov[g * 4 + 3]);
            uint2 st = make_uint2(lo.u, hi.u);
            *(uint2*)&xr[mt * 32 + 8 * g + 4 * hl] = st;
        }
    }
    if (hl == 0) Lp[split * NROWS + j] = lsum;
}

// ---------------------------------------------------------------------------
// Combine K-split partials: xb[j][dv] = (Sum_r Xp[r][j][dv]) / (Sum_r L[r][j])
// Thread handles 8 dv of one row.
// ---------------------------------------------------------------------------
__global__ __launch_bounds__(256) void combine_attn(
    const unsigned short* __restrict__ Xp, const float* __restrict__ Lp,
    unsigned short* __restrict__ xb)
{
    int i = blockIdx.x * 256 + threadIdx.x;
    int j = i >> 3, dc = (i & 7) * 8;
    U4H a, b;
    a.u = *(const uint4*)&Xp[(size_t)j * HDIM + dc];
    b.u = *(const uint4*)&Xp[((size_t)NROWS + j) * HDIM + dc];
    float inv = 1.0f / (Lp[j] + Lp[NROWS + j]);
    U4H o;
    #pragma unroll
    for (int p = 0; p < 4; p++) {
        float s0 = ((float)a.h[2 * p]     + (float)b.h[2 * p])     * inv;
        float s1 = ((float)a.h[2 * p + 1] + (float)b.h[2 * p + 1]) * inv;
        h16x2 pk = pkrtz(s0, s1);
        o.h[2 * p] = pk[0]; o.h[2 * p + 1] = pk[1];
    }
    *(uint4*)&xb[(size_t)j * HDIM + dc] = o.u;
}

// ---------------------------------------------------------------------------
extern "C" void kernel_launch(void* const* d_in, const int* in_sizes, int n_in,
                              void* d_out, int out_size, void* d_ws, size_t ws_size,
                              hipStream_t stream) {
    const float* query = (const float*)d_in[0];
    const float* key_  = (const float*)d_in[1];
    const float* value = (const float*)d_in[2];
    const float* mask  = (const float*)d_in[3];
    const float* Wq = (const float*)d_in[4];
    const float* bq = (const float*)d_in[5];
    const float* Wk = (const float*)d_in[6];
    const float* bk = (const float*)d_in[7];
    const float* Wv = (const float*)d_in[8];
    const float* bv = (const float*)d_in[9];
    const float* Wo = (const float*)d_in[10];
    const float* bo = (const float*)d_in[11];
    float* out = (float*)d_out;

    const size_t NP = (size_t)BATCH * SEQ * DMODEL;   // 4194304
    unsigned short* ws   = (unsigned short*)d_ws;
    unsigned short* qb16 = ws;
    unsigned short* kb16 = qb16 + NP;
    unsigned short* vT16 = kb16 + NP;
    unsigned short* xb16 = vT16 + NP;
    unsigned short* em16 = xb16 + NP;                 // SEQ*SEQ f16
    unsigned short* Xp16 = em16 + (size_t)SEQ * SEQ;  // KSPLIT*NROWS*64 f16
    unsigned short* WqT  = Xp16 + (size_t)KSPLIT * NROWS * HDIM;
    unsigned short* WkT  = WqT + DMODEL * DMODEL;
    unsigned short* WvT  = WkT + DMODEL * DMODEL;
    unsigned short* WoT  = WvT + DMODEL * DMODEL;
    float* Lp = (float*)(WoT + DMODEL * DMODEL);      // KSPLIT*NROWS f32
    // total ws: (4*4.19M + 4.19M + 8.39M + 1.05M)*2B + 0.5MB ~= 61 MB

    transpose_cast_w<<<dim3(16, 16, 4), 256, 0, stream>>>(
        Wq, Wk, Wv, Wo, WqT, WkT, WvT, WoT);
    prep_mask<<<dim3(SEQ * SEQ / 4 / 256), 256, 0, stream>>>(mask, em16);

    QKVArgs qa;
    qa.A0 = query; qa.A1 = key_; qa.A2 = value;
    qa.W0 = WqT;   qa.W1 = WkT;  qa.W2 = WvT;
    qa.b0 = bq;    qa.b1 = bk;   qa.b2 = bv;
    qa.o0 = qb16;  qa.o1 = kb16; qa.o2 = vT16;   // V written transposed
    gemm_qkv<<<dim3(DMODEL / 128, BATCH * SEQ / 128, 3), 256, 0, stream>>>(qa);

    attn5<<<dim3(BATCH * NHEAD, SEQ / 128, KSPLIT), 256, 0, stream>>>(
        qb16, kb16, vT16, em16, Xp16, Lp);

    combine_attn<<<dim3(NROWS * 8 / 256), 256, 0, stream>>>(Xp16, Lp, xb16);

    gemm_fin<<<dim3(DMODEL / 128, BATCH * SEQ / 128), 256, 0, stream>>>(
        xb16, WoT, bo, out);
}